// Round 4
// baseline (1129.773 us; speedup 1.0000x reference)
//
#include <hip/hip_runtime.h>
#include <hip/hip_fp16.h>

static constexpr unsigned TSIZE = 1u << 19;
static constexpr unsigned TMASK = TSIZE - 1u;

union H2U { __half2 h; unsigned u; };

// ---- prologue: fp32 tables -> fp16 in workspace (ws re-poisoned every call) ----
__global__ __launch_bounds__(256)
void cvt_tables(const float4* __restrict__ in, __half2* __restrict__ out, int n4)
{
    int i = blockIdx.x * 256 + threadIdx.x;
    if (i < n4) {
        float4 v = in[i];
        out[2 * i]     = __floats2half2_rn(v.x, v.y);
        out[2 * i + 1] = __floats2half2_rn(v.z, v.w);
    }
}

// One hash-grid level: 8 corner gathers + trilinear blend. tab pre-offset to level.
__device__ __forceinline__ void hash_level(float px, float py, float pz, int l,
                                           const __half2* __restrict__ tab,
                                           float& e0, float& e1)
{
    const float res = 200.0f * (float)(1 << l);
    const float fx = px * res, fy = py * res, fz = pz * res;
    const float flx = floorf(fx), fly = floorf(fy), flz = floorf(fz);
    const float frx = fx - flx, fry = fy - fly, frz = fz - flz;
    const unsigned bx = (unsigned)flx, by = (unsigned)fly, bz = (unsigned)flz;
    const unsigned hy0 = by * 2654435761u, hy1 = (by + 1u) * 2654435761u;
    const unsigned hz0 = bz * 805459861u,  hz1 = (bz + 1u) * 805459861u;
    const float wx[2] = {1.0f - frx, frx};
    const float wy[2] = {1.0f - fry, fry};
    const float wz[2] = {1.0f - frz, frz};
    e0 = 0.0f; e1 = 0.0f;
    #pragma unroll
    for (int c = 0; c < 8; ++c) {
        unsigned h = (bx + (unsigned)(c & 1))
                   ^ ((c & 2) ? hy1 : hy0)
                   ^ ((c & 4) ? hz1 : hz0);
        __half2 fv = tab[h & TMASK];            // random 4B gather, L2-resident
        float2 f = __half22float2(fv);
        float w = wx[c & 1] * wy[(c >> 1) & 1] * wz[(c >> 2) & 1];
        e0 = fmaf(f.x, w, e0);
        e1 = fmaf(f.y, w, e1);
    }
}

// Stage xyz [256*3 floats] through LDS with non-temporal global reads.
__device__ __forceinline__ void stage_xyz(const float* __restrict__ xyz, int bbase, int N,
                                          float* sxyz, float& px, float& py, float& pz)
{
    const int g3 = bbase * 3;
    #pragma unroll
    for (int t = 0; t < 3; ++t) {
        int sidx = (int)threadIdx.x + t * 256;
        int g = g3 + sidx;
        sxyz[sidx] = (g < 3 * N) ? __builtin_nontemporal_load(&xyz[g]) : 0.0f;
    }
    __syncthreads();
    px = (sxyz[threadIdx.x * 3 + 0] + 5.0f) * 0.1f;
    py = (sxyz[threadIdx.x * 3 + 1] + 5.0f) * 0.1f;
    pz = (sxyz[threadIdx.x * 3 + 2] + 5.0f) * 0.1f;
}

// ---- pass A: levels 0,1 (4 MB fp16 working set = one XCD L2) -> packed fp16 partials ----
__global__ __launch_bounds__(256, 8)
void encode01(const float* __restrict__ xyz, const __half2* __restrict__ tab16,
              unsigned long long* __restrict__ enc01, int N)
{
    __shared__ float sxyz[768];
    const int bbase = blockIdx.x * 256;
    const int i = bbase + (int)threadIdx.x;
    float px, py, pz;
    stage_xyz(xyz, bbase, N, sxyz, px, py, pz);

    float e0, e1, e2, e3;
    hash_level(px, py, pz, 0, tab16,         e0, e1);
    hash_level(px, py, pz, 1, tab16 + TSIZE, e2, e3);

    H2U a, b;
    a.h = __floats2half2_rn(e0, e1);
    b.h = __floats2half2_rn(e2, e3);
    if (i < N) {
        unsigned long long v = (unsigned long long)a.u
                             | ((unsigned long long)b.u << 32);
        __builtin_nontemporal_store(v, &enc01[i]);
    }
}

// ---- pass B: levels 2,3 (other 4 MB) + MLP, fully unrolled (no dynamic reg indexing) ----
__global__ __launch_bounds__(256, 4)
void mlp23(const float* __restrict__ xyz, const __half2* __restrict__ tab16,
           const unsigned long long* __restrict__ enc01,
           const float* __restrict__ Win, const float* __restrict__ Wh,
           const float* __restrict__ Wout, float* __restrict__ out, int N)
{
    __shared__ float sxyz[768];
    const int bbase = blockIdx.x * 256;
    const int i = bbase + (int)threadIdx.x;
    float px, py, pz;
    stage_xyz(xyz, bbase, N, sxyz, px, py, pz);

    float enc[8];
    {   // levels 0,1 partials from pass A
        unsigned long long v = __builtin_nontemporal_load(&enc01[i < N ? i : 0]);
        H2U a, b; a.u = (unsigned)v; b.u = (unsigned)(v >> 32);
        float2 f01 = __half22float2(a.h);
        float2 f23 = __half22float2(b.h);
        enc[0] = f01.x; enc[1] = f01.y; enc[2] = f23.x; enc[3] = f23.y;
    }
    hash_level(px, py, pz, 2, tab16 + 2 * TSIZE, enc[4], enc[5]);
    hash_level(px, py, pz, 3, tab16 + 3 * TSIZE, enc[6], enc[7]);

    // layer 1: h1 = leaky_relu(enc @ Win) — all indices compile-time constants
    float h1[64];
    #pragma unroll
    for (int j = 0; j < 64; ++j) h1[j] = 0.0f;
    #pragma unroll
    for (int k = 0; k < 8; ++k) {
        const float e = enc[k];
        #pragma unroll
        for (int j = 0; j < 64; ++j)
            h1[j] = fmaf(e, Win[k * 64 + j], h1[j]);
    }
    #pragma unroll
    for (int j = 0; j < 64; ++j)
        h1[j] = (h1[j] >= 0.0f) ? h1[j] : 0.01f * h1[j];

    // layers 2+3 fused, j blocked by 16; k and jj FULLY unrolled (static reg indices),
    // j0 stays a runtime loop (only weight addresses depend on it).
    float sdf = 0.0f;
    for (int j0 = 0; j0 < 64; j0 += 16) {
        float acc[16];
        #pragma unroll
        for (int jj = 0; jj < 16; ++jj) acc[jj] = 0.0f;
        #pragma unroll
        for (int k = 0; k < 64; ++k) {
            const float hk = h1[k];
            #pragma unroll
            for (int jj = 0; jj < 16; ++jj)
                acc[jj] = fmaf(hk, Wh[k * 64 + j0 + jj], acc[jj]);
        }
        #pragma unroll
        for (int jj = 0; jj < 16; ++jj) {
            float a = acc[jj];
            a = (a >= 0.0f) ? a : 0.01f * a;
            sdf = fmaf(a, Wout[j0 + jj], sdf);
        }
    }

    if (i < N) __builtin_nontemporal_store(sdf * 0.1f, &out[i]);
}

// ---- fallback (ws too small): monolithic fp32, no dynamic reg indexing ----
__global__ __launch_bounds__(256, 4)
void resnet_mono(const float* __restrict__ xyz, const float* __restrict__ tables,
                 const float* __restrict__ Win, const float* __restrict__ Wh,
                 const float* __restrict__ Wout, float* __restrict__ out, int N)
{
    __shared__ float sxyz[768];
    const int bbase = blockIdx.x * 256;
    const int i = bbase + (int)threadIdx.x;
    float px, py, pz;
    stage_xyz(xyz, bbase, N, sxyz, px, py, pz);

    float enc[8];
    #pragma unroll
    for (int l = 0; l < 4; ++l) {
        const float res = 200.0f * (float)(1 << l);
        const float fx = px * res, fy = py * res, fz = pz * res;
        const float flx = floorf(fx), fly = floorf(fy), flz = floorf(fz);
        const float frx = fx - flx, fry = fy - fly, frz = fz - flz;
        const unsigned bx = (unsigned)flx, by = (unsigned)fly, bz = (unsigned)flz;
        const unsigned hy0 = by * 2654435761u, hy1 = (by + 1u) * 2654435761u;
        const unsigned hz0 = bz * 805459861u,  hz1 = (bz + 1u) * 805459861u;
        const float wx[2] = {1.0f - frx, frx};
        const float wy[2] = {1.0f - fry, fry};
        const float wz[2] = {1.0f - frz, frz};
        const float2* tab = (const float2*)tables + (size_t)l * TSIZE;
        float e0 = 0.0f, e1 = 0.0f;
        #pragma unroll
        for (int c = 0; c < 8; ++c) {
            unsigned h = (bx + (unsigned)(c & 1))
                       ^ ((c & 2) ? hy1 : hy0)
                       ^ ((c & 4) ? hz1 : hz0);
            float2 f = tab[h & TMASK];
            float w = wx[c & 1] * wy[(c >> 1) & 1] * wz[(c >> 2) & 1];
            e0 = fmaf(f.x, w, e0);
            e1 = fmaf(f.y, w, e1);
        }
        enc[2 * l] = e0; enc[2 * l + 1] = e1;
    }

    float h1[64];
    #pragma unroll
    for (int j = 0; j < 64; ++j) h1[j] = 0.0f;
    #pragma unroll
    for (int k = 0; k < 8; ++k) {
        const float e = enc[k];
        #pragma unroll
        for (int j = 0; j < 64; ++j)
            h1[j] = fmaf(e, Win[k * 64 + j], h1[j]);
    }
    #pragma unroll
    for (int j = 0; j < 64; ++j)
        h1[j] = (h1[j] >= 0.0f) ? h1[j] : 0.01f * h1[j];

    float sdf = 0.0f;
    for (int j0 = 0; j0 < 64; j0 += 16) {
        float acc[16];
        #pragma unroll
        for (int jj = 0; jj < 16; ++jj) acc[jj] = 0.0f;
        #pragma unroll
        for (int k = 0; k < 64; ++k) {
            const float hk = h1[k];
            #pragma unroll
            for (int jj = 0; jj < 16; ++jj)
                acc[jj] = fmaf(hk, Wh[k * 64 + j0 + jj], acc[jj]);
        }
        #pragma unroll
        for (int jj = 0; jj < 16; ++jj) {
            float a = acc[jj];
            a = (a >= 0.0f) ? a : 0.01f * a;
            sdf = fmaf(a, Wout[j0 + jj], sdf);
        }
    }
    if (i < N) out[i] = sdf * 0.1f;
}

extern "C" void kernel_launch(void* const* d_in, const int* in_sizes, int n_in,
                              void* d_out, int out_size, void* d_ws, size_t ws_size,
                              hipStream_t stream) {
    const float* xyz    = (const float*)d_in[0];
    const float* tables = (const float*)d_in[1];
    const float* Win    = (const float*)d_in[2];
    const float* Wh     = (const float*)d_in[3];
    const float* Wout   = (const float*)d_in[4];
    float* out = (float*)d_out;

    const int N = in_sizes[0] / 3;               // xyz is [N,3]
    const int blocks = (N + 255) / 256;

    const int tab_floats = in_sizes[1];          // 4 * 2^19 * 2
    const size_t tab16_bytes = (size_t)tab_floats * 2;       // 8 MB
    const size_t enc01_bytes = (size_t)N * 8;                // 16 MB

    if (ws_size >= tab16_bytes + enc01_bytes) {
        __half2* tab16 = (__half2*)d_ws;
        unsigned long long* enc01 = (unsigned long long*)((char*)d_ws + tab16_bytes);
        int n4 = tab_floats / 4;
        hipLaunchKernelGGL(cvt_tables, dim3((n4 + 255) / 256), dim3(256), 0, stream,
                           (const float4*)tables, tab16, n4);
        hipLaunchKernelGGL(encode01, dim3(blocks), dim3(256), 0, stream,
                           xyz, tab16, enc01, N);
        hipLaunchKernelGGL(mlp23, dim3(blocks), dim3(256), 0, stream,
                           xyz, tab16, enc01, Win, Wh, Wout, out, N);
    } else {
        hipLaunchKernelGGL(resnet_mono, dim3(blocks), dim3(256), 0, stream,
                           xyz, tables, Win, Wh, Wout, out, N);
    }
}

// Round 5
// 324.904 us; speedup vs baseline: 3.4773x; 3.4773x over previous
//
#include <hip/hip_runtime.h>
#include <hip/hip_fp16.h>

static constexpr unsigned TSIZE = 1u << 19;
static constexpr unsigned TMASK = TSIZE - 1u;

typedef _Float16 f16;
typedef f16   f16x8 __attribute__((ext_vector_type(8)));
typedef float f32x4 __attribute__((ext_vector_type(4)));

union H2U { __half2 h; unsigned u; };

// ---- prologue: fp32 tables -> fp16 in workspace (ws re-poisoned every call) ----
__global__ __launch_bounds__(256)
void cvt_tables(const float4* __restrict__ in, __half2* __restrict__ out, int n4)
{
    int i = blockIdx.x * 256 + threadIdx.x;
    if (i < n4) {
        float4 v = in[i];
        out[2 * i]     = __floats2half2_rn(v.x, v.y);
        out[2 * i + 1] = __floats2half2_rn(v.z, v.w);
    }
}

// One hash-grid level: 8 corner gathers + trilinear blend. tab pre-offset to level.
__device__ __forceinline__ void hash_level(float px, float py, float pz, int l,
                                           const __half2* __restrict__ tab,
                                           float& e0, float& e1)
{
    const float res = 200.0f * (float)(1 << l);
    const float fx = px * res, fy = py * res, fz = pz * res;
    const float flx = floorf(fx), fly = floorf(fy), flz = floorf(fz);
    const float frx = fx - flx, fry = fy - fly, frz = fz - flz;
    const unsigned bx = (unsigned)flx, by = (unsigned)fly, bz = (unsigned)flz;
    const unsigned hy0 = by * 2654435761u, hy1 = (by + 1u) * 2654435761u;
    const unsigned hz0 = bz * 805459861u,  hz1 = (bz + 1u) * 805459861u;
    const float wx[2] = {1.0f - frx, frx};
    const float wy[2] = {1.0f - fry, fry};
    const float wz[2] = {1.0f - frz, frz};
    e0 = 0.0f; e1 = 0.0f;
    #pragma unroll
    for (int c = 0; c < 8; ++c) {
        unsigned h = (bx + (unsigned)(c & 1))
                   ^ ((c & 2) ? hy1 : hy0)
                   ^ ((c & 4) ? hz1 : hz0);
        __half2 fv = tab[h & TMASK];            // random 4B gather, L2-resident
        float2 f = __half22float2(fv);
        float w = wx[c & 1] * wy[(c >> 1) & 1] * wz[(c >> 2) & 1];
        e0 = fmaf(f.x, w, e0);
        e1 = fmaf(f.y, w, e1);
    }
}

// Stage xyz [256*3 floats] through LDS with non-temporal global reads.
__device__ __forceinline__ void stage_xyz(const float* __restrict__ xyz, int bbase, int N,
                                          float* sxyz, float& px, float& py, float& pz)
{
    const int g3 = bbase * 3;
    #pragma unroll
    for (int t = 0; t < 3; ++t) {
        int sidx = (int)threadIdx.x + t * 256;
        int g = g3 + sidx;
        sxyz[sidx] = (g < 3 * N) ? __builtin_nontemporal_load(&xyz[g]) : 0.0f;
    }
    __syncthreads();
    px = (sxyz[threadIdx.x * 3 + 0] + 5.0f) * 0.1f;
    py = (sxyz[threadIdx.x * 3 + 1] + 5.0f) * 0.1f;
    pz = (sxyz[threadIdx.x * 3 + 2] + 5.0f) * 0.1f;
}

// ---- pass A: levels 0,1 (4 MB fp16 = one XCD L2) -> packed fp16 partials ----
__global__ __launch_bounds__(256, 8)
void encode01(const float* __restrict__ xyz, const __half2* __restrict__ tab16,
              unsigned long long* __restrict__ enc01, int N)
{
    __shared__ float sxyz[768];
    const int bbase = blockIdx.x * 256;
    const int i = bbase + (int)threadIdx.x;
    float px, py, pz;
    stage_xyz(xyz, bbase, N, sxyz, px, py, pz);

    float e0, e1, e2, e3;
    hash_level(px, py, pz, 0, tab16,         e0, e1);
    hash_level(px, py, pz, 1, tab16 + TSIZE, e2, e3);

    H2U a, b;
    a.h = __floats2half2_rn(e0, e1);
    b.h = __floats2half2_rn(e2, e3);
    if (i < N) {
        unsigned long long v = (unsigned long long)a.u
                             | ((unsigned long long)b.u << 32);
        __builtin_nontemporal_store(v, &enc01[i]);
    }
}

// ---- pass B: levels 2,3 + fully-fused MLP (layer2 on MFMA) ----
// Per wave: 64 points. Layer1 per-thread fp32 -> f16 staged in LDS ->
// MFMA 16x16x32_f16 (A: h1 64x64, B: Wh 64x64) -> layer3 epilogue + shfl reduce.
static constexpr int H1_STRIDE = 72;   // f16 units; 144 B row, 16B-aligned, bank-spread

__global__ __launch_bounds__(256, 2)
void mlp23_mfma(const float* __restrict__ xyz, const __half2* __restrict__ tab16,
                const unsigned long long* __restrict__ enc01,
                const float* __restrict__ Win, const float* __restrict__ Wh,
                const float* __restrict__ Wout, float* __restrict__ out, int N)
{
    __shared__ float sxyz[768];
    __shared__ f16 h1s[256 * H1_STRIDE];       // 36 KB

    const int bbase = blockIdx.x * 256;
    const int i = bbase + (int)threadIdx.x;
    float px, py, pz;
    stage_xyz(xyz, bbase, N, sxyz, px, py, pz);

    float enc[8];
    {   // levels 0,1 partials from pass A
        unsigned long long v = __builtin_nontemporal_load(&enc01[i < N ? i : 0]);
        H2U a, b; a.u = (unsigned)v; b.u = (unsigned)(v >> 32);
        float2 f01 = __half22float2(a.h);
        float2 f23 = __half22float2(b.h);
        enc[0] = f01.x; enc[1] = f01.y; enc[2] = f23.x; enc[3] = f23.y;
    }
    hash_level(px, py, pz, 2, tab16 + 2 * TSIZE, enc[4], enc[5]);
    hash_level(px, py, pz, 3, tab16 + 3 * TSIZE, enc[6], enc[7]);

    // ---- layer 1 per-thread fp32 (h1[64] live only in this phase) ----
    float h1[64];
    #pragma unroll
    for (int j = 0; j < 64; ++j) h1[j] = 0.0f;
    #pragma unroll
    for (int k = 0; k < 8; ++k) {
        const float e = enc[k];
        #pragma unroll
        for (int j = 0; j < 64; ++j)
            h1[j] = fmaf(e, Win[k * 64 + j], h1[j]);
    }
    // leaky + convert + stage to LDS (8x ds_write_b128 per thread)
    {
        f16* row = &h1s[(int)threadIdx.x * H1_STRIDE];
        #pragma unroll
        for (int jj = 0; jj < 8; ++jj) {
            f16x8 v;
            #pragma unroll
            for (int e = 0; e < 8; ++e) {
                float a = h1[jj * 8 + e];
                a = (a >= 0.0f) ? a : 0.01f * a;
                v[e] = (f16)a;
            }
            *(f16x8*)(row + jj * 8) = v;
        }
    }
    __syncthreads();

    const int wave = (int)threadIdx.x >> 6;
    const int lane = (int)threadIdx.x & 63;
    const int c = lane & 15;          // column / M-index within tile
    const int q = lane >> 4;          // quad
    const f16* wbase = &h1s[wave * 64 * H1_STRIDE];

    // ---- B fragments: Wh[k][n], k=kt*32+q*8+j, n=nt*16+c (fp32 global, L1-hot) ----
    f16x8 bfrag[2][4];
    #pragma unroll
    for (int kt = 0; kt < 2; ++kt)
        #pragma unroll
        for (int nt = 0; nt < 4; ++nt)
            #pragma unroll
            for (int j = 0; j < 8; ++j)
                bfrag[kt][nt][j] = (f16)Wh[(kt * 32 + q * 8 + j) * 64 + nt * 16 + c];

    // ---- layer 2: 4 Mtiles x 4 Ntiles x 2 Ktiles of mfma_f32_16x16x32_f16 ----
    f32x4 Ct[4][4];
    #pragma unroll
    for (int mt = 0; mt < 4; ++mt)
        #pragma unroll
        for (int nt = 0; nt < 4; ++nt)
            Ct[mt][nt] = (f32x4){0.f, 0.f, 0.f, 0.f};

    #pragma unroll
    for (int mt = 0; mt < 4; ++mt) {
        #pragma unroll
        for (int kt = 0; kt < 2; ++kt) {
            // A[m=c][k=kt*32+q*8+j] for point mt*16+c of this wave
            const f16x8 a = *(const f16x8*)&wbase[(mt * 16 + c) * H1_STRIDE + kt * 32 + q * 8];
            #pragma unroll
            for (int nt = 0; nt < 4; ++nt)
                Ct[mt][nt] = __builtin_amdgcn_mfma_f32_16x16x32_f16(a, bfrag[kt][nt], Ct[mt][nt], 0, 0, 0);
        }
    }

    // ---- layer 3: leaky(h2) @ Wout, C-layout: row(point)=q*4+r, col(feat)=c ----
    float acc3[4][4];                 // [mt][r]
    #pragma unroll
    for (int mt = 0; mt < 4; ++mt)
        #pragma unroll
        for (int r = 0; r < 4; ++r) acc3[mt][r] = 0.0f;

    #pragma unroll
    for (int nt = 0; nt < 4; ++nt) {
        const float wo = Wout[nt * 16 + c];
        #pragma unroll
        for (int mt = 0; mt < 4; ++mt)
            #pragma unroll
            for (int r = 0; r < 4; ++r) {
                float v = Ct[mt][nt][r];
                v = (v >= 0.0f) ? v : 0.01f * v;
                acc3[mt][r] = fmaf(v, wo, acc3[mt][r]);
            }
    }
    // reduce across the 16 feature-lanes (bits 0..3 of lane)
    #pragma unroll
    for (int mask = 1; mask <= 8; mask <<= 1)
        #pragma unroll
        for (int mt = 0; mt < 4; ++mt)
            #pragma unroll
            for (int r = 0; r < 4; ++r)
                acc3[mt][r] += __shfl_xor(acc3[mt][r], mask, 64);

    if (c == 0) {
        #pragma unroll
        for (int mt = 0; mt < 4; ++mt)
            #pragma unroll
            for (int r = 0; r < 4; ++r) {
                int p = bbase + wave * 64 + mt * 16 + q * 4 + r;
                if (p < N) out[p] = acc3[mt][r] * 0.1f;
            }
    }
}

// ---- fallback (ws too small): monolithic fp32 ----
__global__ __launch_bounds__(256, 2)
void resnet_mono(const float* __restrict__ xyz, const float* __restrict__ tables,
                 const float* __restrict__ Win, const float* __restrict__ Wh,
                 const float* __restrict__ Wout, float* __restrict__ out, int N)
{
    __shared__ float sxyz[768];
    const int bbase = blockIdx.x * 256;
    const int i = bbase + (int)threadIdx.x;
    float px, py, pz;
    stage_xyz(xyz, bbase, N, sxyz, px, py, pz);

    float enc[8];
    #pragma unroll
    for (int l = 0; l < 4; ++l) {
        const float res = 200.0f * (float)(1 << l);
        const float fx = px * res, fy = py * res, fz = pz * res;
        const float flx = floorf(fx), fly = floorf(fy), flz = floorf(fz);
        const float frx = fx - flx, fry = fy - fly, frz = fz - flz;
        const unsigned bx = (unsigned)flx, by = (unsigned)fly, bz = (unsigned)flz;
        const unsigned hy0 = by * 2654435761u, hy1 = (by + 1u) * 2654435761u;
        const unsigned hz0 = bz * 805459861u,  hz1 = (bz + 1u) * 805459861u;
        const float wx[2] = {1.0f - frx, frx};
        const float wy[2] = {1.0f - fry, fry};
        const float wz[2] = {1.0f - frz, frz};
        const float2* tab = (const float2*)tables + (size_t)l * TSIZE;
        float e0 = 0.0f, e1 = 0.0f;
        #pragma unroll
        for (int cc = 0; cc < 8; ++cc) {
            unsigned h = (bx + (unsigned)(cc & 1))
                       ^ ((cc & 2) ? hy1 : hy0)
                       ^ ((cc & 4) ? hz1 : hz0);
            float2 f = tab[h & TMASK];
            float w = wx[cc & 1] * wy[(cc >> 1) & 1] * wz[(cc >> 2) & 1];
            e0 = fmaf(f.x, w, e0);
            e1 = fmaf(f.y, w, e1);
        }
        enc[2 * l] = e0; enc[2 * l + 1] = e1;
    }

    float h1[64];
    #pragma unroll
    for (int j = 0; j < 64; ++j) h1[j] = 0.0f;
    #pragma unroll
    for (int k = 0; k < 8; ++k) {
        const float e = enc[k];
        #pragma unroll
        for (int j = 0; j < 64; ++j)
            h1[j] = fmaf(e, Win[k * 64 + j], h1[j]);
    }
    #pragma unroll
    for (int j = 0; j < 64; ++j)
        h1[j] = (h1[j] >= 0.0f) ? h1[j] : 0.01f * h1[j];

    float sdf = 0.0f;
    #pragma unroll
    for (int j0 = 0; j0 < 64; j0 += 16) {
        float acc[16];
        #pragma unroll
        for (int jj = 0; jj < 16; ++jj) acc[jj] = 0.0f;
        #pragma unroll
        for (int k = 0; k < 64; ++k) {
            const float hk = h1[k];
            #pragma unroll
            for (int jj = 0; jj < 16; ++jj)
                acc[jj] = fmaf(hk, Wh[k * 64 + j0 + jj], acc[jj]);
        }
        #pragma unroll
        for (int jj = 0; jj < 16; ++jj) {
            float a = acc[jj];
            a = (a >= 0.0f) ? a : 0.01f * a;
            sdf = fmaf(a, Wout[j0 + jj], sdf);
        }
    }
    if (i < N) out[i] = sdf * 0.1f;
}

extern "C" void kernel_launch(void* const* d_in, const int* in_sizes, int n_in,
                              void* d_out, int out_size, void* d_ws, size_t ws_size,
                              hipStream_t stream) {
    const float* xyz    = (const float*)d_in[0];
    const float* tables = (const float*)d_in[1];
    const float* Win    = (const float*)d_in[2];
    const float* Wh     = (const float*)d_in[3];
    const float* Wout   = (const float*)d_in[4];
    float* out = (float*)d_out;

    const int N = in_sizes[0] / 3;               // xyz is [N,3]
    const int blocks = (N + 255) / 256;

    const int tab_floats = in_sizes[1];          // 4 * 2^19 * 2
    const size_t tab16_bytes = (size_t)tab_floats * 2;       // 8 MB
    const size_t enc01_bytes = (size_t)N * 8;                // 16 MB

    if (ws_size >= tab16_bytes + enc01_bytes) {
        __half2* tab16 = (__half2*)d_ws;
        unsigned long long* enc01 = (unsigned long long*)((char*)d_ws + tab16_bytes);
        int n4 = tab_floats / 4;
        hipLaunchKernelGGL(cvt_tables, dim3((n4 + 255) / 256), dim3(256), 0, stream,
                           (const float4*)tables, tab16, n4);
        hipLaunchKernelGGL(encode01, dim3(blocks), dim3(256), 0, stream,
                           xyz, tab16, enc01, N);
        hipLaunchKernelGGL(mlp23_mfma, dim3(blocks), dim3(256), 0, stream,
                           xyz, tab16, enc01, Win, Wh, Wout, out, N);
    } else {
        hipLaunchKernelGGL(resnet_mono, dim3(blocks), dim3(256), 0, stream,
                           xyz, tables, Win, Wh, Wout, out, N);
    }
}